// Round 2
// baseline (105.211 us; speedup 1.0000x reference)
//
#include <hip/hip_runtime.h>
#include <hip/hip_bf16.h>
#include <cstdint>
#include <cstddef>

// Problem constants (B=4, H=16, S=4096, E=128)
#define S_LEN 4096
#define E_DIM 128
#define NROWS (4 * 16 * 4096)   // 262144 token rows
#define TOK_PER_BLK 128         // tokens per block (2 strips of 16 per wave)
#define NSTRIP 2

typedef __attribute__((ext_vector_type(8))) short bh8;   // 8 bf16 (4 VGPRs) MFMA frag
typedef __attribute__((ext_vector_type(4))) float f4;    // MFMA accumulator

__device__ __forceinline__ unsigned short f2bf(float f) {
    union { float f; uint32_t u; } v; v.f = f;
    uint32_t r = v.u + 0x7FFFu + ((v.u >> 16) & 1u);   // round-to-nearest-even
    return (unsigned short)(r >> 16);
}

// ---------- prologue: A = (S - S^T)/2, plus interleaved cos/sin table ----------
// csT[s*128 + 2*f] = cos(pos[s]*freq[f]),  csT[s*128 + 2*f + 1] = sin(...)
__global__ void k_prep(const float* __restrict__ Sc, const float* __restrict__ pos,
                       float* __restrict__ A, float* __restrict__ csT, int doTable) {
    int b = blockIdx.x;
    if (b < 16) {
        for (int e = b * 256 + threadIdx.x; e < 16384; e += 4096) {
            int i = e >> 7, j = e & 127;
            A[e] = 0.5f * (Sc[i * 128 + j] - Sc[j * 128 + i]);
        }
    } else if (doTable) {
        int t = (b - 16) * 256 + threadIdx.x;
        for (int e = t; e < S_LEN * 64; e += 64 * 256) {
            int s = e >> 6, f = e & 63;
            // freq = 10000^(-f/64) = exp2(-f * log2(10000)/64)
            float freq = exp2f(-0.20762050593046015f * (float)f);
            float ang = pos[s] * freq;
            float sv, cv;
            sincosf(ang, &sv, &cv);
            csT[s * 128 + 2 * f]     = cv;
            csT[s * 128 + 2 * f + 1] = sv;
        }
    }
}

// ---------- A2 = A*A (f32, tiny) ----------
__global__ void k_sq(const float* __restrict__ M, float* __restrict__ O) {
    int t = blockIdx.x * 256 + threadIdx.x;      // 32 blocks
    for (int e = t; e < 16384; e += 8192) {
        int i = e >> 7, j = e & 127;
        float acc = 0.f;
        for (int k = 0; k < 128; ++k) acc += M[i * 128 + k] * M[k * 128 + j];
        O[e] = acc;
    }
}

// ---------- A4 = A2*A2  and  M1 = (I - 2A + A2)(I + A2) ----------
__global__ void k_step2(const float* __restrict__ A, const float* __restrict__ A2,
                        float* __restrict__ A4, float* __restrict__ M1) {
    int b = blockIdx.x;                          // 64 blocks
    if (b < 32) {
        int t = b * 256 + threadIdx.x;
        for (int e = t; e < 16384; e += 8192) {
            int i = e >> 7, j = e & 127;
            float acc = 0.f;
            for (int k = 0; k < 128; ++k) acc += A2[i * 128 + k] * A2[k * 128 + j];
            A4[e] = acc;
        }
    } else {
        int t = (b - 32) * 256 + threadIdx.x;
        for (int e = t; e < 16384; e += 8192) {
            int i = e >> 7, j = e & 127;
            float acc = 0.f;
            for (int k = 0; k < 128; ++k) {
                float bik = A2[i * 128 + k] - 2.0f * A[i * 128 + k] + (k == i ? 1.0f : 0.0f);
                float ckj = A2[k * 128 + j] + (k == j ? 1.0f : 0.0f);
                acc += bik * ckj;
            }
            M1[e] = acc;
        }
    }
}

// ---------- P = M1*(I + A4);  store Q = P - I as bf16 ----------
__global__ void k_finalP(const float* __restrict__ M1, const float* __restrict__ A4,
                         unsigned short* __restrict__ Qb) {
    int t = blockIdx.x * 256 + threadIdx.x;      // 32 blocks
    for (int e = t; e < 16384; e += 8192) {
        int i = e >> 7, j = e & 127;
        float acc = M1[e];
        for (int k = 0; k < 128; ++k) acc += M1[i * 128 + k] * A4[k * 128 + j];
        if (i == j) acc -= 1.0f;                 // Q = P - I
        Qb[e] = f2bf(acc);
    }
}

// ---------- main fused kernel: out = RoPE(x + x*Q^T) ----------
// Swapped MFMA: acc[t] = D[n][m] = sum_k Q[n][k]*x[m][k].
// C/D layout col=lane&15 -> token m = m0+llo; row=lhi*4+reg -> n = t*16+lhi*4+r
// => each acc reg quad = 4 CONSECUTIVE n for one token -> float4 epilogue.
template <bool USE_TABLE>
__global__ __launch_bounds__(256, 4) void k_main(const float* __restrict__ x,
        const unsigned short* __restrict__ Qb,
        const float* __restrict__ csT,
        const float* __restrict__ pos, float* __restrict__ out) {
    // Q staged in LDS: 128 rows padded to 136 shorts (272 B)
    __shared__ unsigned short Plds[128 * 136];
    #pragma unroll
    for (int i = 0; i < 8; ++i) {
        int chunk = i * 256 + threadIdx.x;       // 2048 chunks of 8 shorts (16 B)
        int row = chunk >> 4, c8 = chunk & 15;
        bh8 v = *(const bh8*)(Qb + chunk * 8);
        *(bh8*)(&Plds[row * 136 + c8 * 8]) = v;
    }
    __syncthreads();

    const int wave = threadIdx.x >> 6;
    const int lane = threadIdx.x & 63;
    const int lhi = lane >> 4, llo = lane & 15;

    #pragma unroll
    for (int strip = 0; strip < NSTRIP; ++strip) {
        const int m0 = blockIdx.x * TOK_PER_BLK + strip * 64 + wave * 16;
        const int m = m0 + llo;                  // this lane's token for the whole strip
        const int s = m & (S_LEN - 1);

        // x fragment (B-operand): lane holds x[m][k = kk*32 + lhi*8 + e]
        bh8 xfrag[4];
        const float* xr0 = x + (size_t)m * E_DIM + lhi * 8;
        #pragma unroll
        for (int kk = 0; kk < 4; ++kk) {
            f4 v0 = *(const f4*)(xr0 + kk * 32);
            f4 v1 = *(const f4*)(xr0 + kk * 32 + 4);
            bh8 a;
            a[0] = (short)f2bf(v0[0]); a[1] = (short)f2bf(v0[1]);
            a[2] = (short)f2bf(v0[2]); a[3] = (short)f2bf(v0[3]);
            a[4] = (short)f2bf(v1[0]); a[5] = (short)f2bf(v1[1]);
            a[6] = (short)f2bf(v1[2]); a[7] = (short)f2bf(v1[3]);
            xfrag[kk] = a;
        }

        f4 acc[8];
        #pragma unroll
        for (int t = 0; t < 8; ++t) { f4 z = {0.f, 0.f, 0.f, 0.f}; acc[t] = z; }

        // A-operand = Q rows: lane holds Q[n = t*16+llo][k = kk*32+lhi*8+e]
        #pragma unroll
        for (int kk = 0; kk < 4; ++kk) {
            #pragma unroll
            for (int t = 0; t < 8; ++t) {
                bh8 qfrag = *(const bh8*)(&Plds[(t * 16 + llo) * 136 + kk * 32 + lhi * 8]);
                acc[t] = __builtin_amdgcn_mfma_f32_16x16x32_bf16(qfrag, xfrag[kk], acc[t], 0, 0, 0);
            }
        }

        // epilogue: all float4. xt = x + x*Q^T, then rotate-half RoPE.
        const float* xr = x + (size_t)m * E_DIM;
        float* orow = out + (size_t)m * E_DIM;
        float spos = 0.f;
        if constexpr (!USE_TABLE) spos = pos[s];
        #pragma unroll
        for (int t = 0; t < 4; ++t) {
            const int n0 = t * 16 + lhi * 4;     // 4 consecutive n in regs r=0..3
            f4 xlo = *(const f4*)(xr + n0);
            f4 xhi = *(const f4*)(xr + n0 + 64);
            f4 cs_lo, cs_hi;                     // {cos f, sin f, cos f+1, sin f+1}
            if constexpr (USE_TABLE) {
                cs_lo = *(const f4*)(csT + (size_t)s * 128 + n0);        // 2*(n0>>1)==n0
                cs_hi = *(const f4*)(csT + (size_t)s * 128 + 64 + n0);
            } else {
                const int f1 = n0 >> 1;
                float fr_a = exp2f(-0.20762050593046015f * (float)f1);
                float fr_b = fr_a * 0.8659643233600653f;   // 10000^(-1/64)
                float ca, sa, cb, sb;
                sincosf(spos * fr_a, &sa, &ca);
                sincosf(spos * fr_b, &sb, &cb);
                cs_lo[0] = ca; cs_lo[1] = sa; cs_lo[2] = cb; cs_lo[3] = sb;
                sincosf(spos * fr_a * 0.01f, &sa, &ca);    // f1+32 -> *10000^(-1/2)
                sincosf(spos * fr_b * 0.01f, &sb, &cb);
                cs_hi[0] = ca; cs_hi[1] = sa; cs_hi[2] = cb; cs_hi[3] = sb;
            }
            f4 olo, ohi;
            #pragma unroll
            for (int r = 0; r < 4; ++r) {
                float xt1 = acc[t][r] + xlo[r];          // n = n0+r
                float xt2 = acc[t + 4][r] + xhi[r];      // n+64
                float c1 = cs_lo[(r >> 1) * 2], s1 = cs_lo[(r >> 1) * 2 + 1];
                float c2 = cs_hi[(r >> 1) * 2], s2 = cs_hi[(r >> 1) * 2 + 1];
                olo[r] = xt1 * c1 - xt2 * s1;
                ohi[r] = xt2 * c2 + xt1 * s2;
            }
            __builtin_nontemporal_store(olo, (f4*)(orow + n0));
            __builtin_nontemporal_store(ohi, (f4*)(orow + n0 + 64));
        }
    }
}

extern "C" void kernel_launch(void* const* d_in, const int* in_sizes, int n_in,
                              void* d_out, int out_size, void* d_ws, size_t ws_size,
                              hipStream_t stream) {
    const float* x   = (const float*)d_in[0];
    const float* pos = (const float*)d_in[1];
    const float* Sc  = (const float*)d_in[2];
    float* out = (float*)d_out;

    char* ws = (char*)d_ws;
    float* A            = (float*)(ws);                    // 64 KB
    float* A2           = (float*)(ws + 65536);            // 64 KB
    float* A4           = (float*)(ws + 131072);           // 64 KB
    float* M1           = (float*)(ws + 196608);           // 64 KB
    unsigned short* Qb  = (unsigned short*)(ws + 262144);  // 32 KB bf16
    float* csT          = (float*)(ws + 294912);           // 2 MB interleaved cos/sin
    const size_t needTable = 294912 + 2 * 1048576;
    bool useTable = ws_size >= needTable;

    k_prep<<<80, 256, 0, stream>>>(Sc, pos, A, csT, useTable ? 1 : 0);
    k_sq<<<32, 256, 0, stream>>>(A, A2);
    k_step2<<<64, 256, 0, stream>>>(A, A2, A4, M1);
    k_finalP<<<32, 256, 0, stream>>>(M1, A4, Qb);
    if (useTable)
        k_main<true><<<NROWS / TOK_PER_BLK, 256, 0, stream>>>(x, Qb, csT, pos, out);
    else
        k_main<false><<<NROWS / TOK_PER_BLK, 256, 0, stream>>>(x, Qb, csT, pos, out);
}